// Round 6
// baseline (535.787 us; speedup 1.0000x reference)
//
#include <hip/hip_runtime.h>

#define B_    4
#define L_    8192
#define D_    1024
#define ROWS_ 32768
#define NCH_  128   // chunks of 64 rows per sequence
#define REP_  6     // DIAGNOSTIC: internal repeats to surface kernels in top-5

typedef __attribute__((ext_vector_type(8))) short  short8;
typedef __attribute__((ext_vector_type(4))) float  floatx4;

__device__ __forceinline__ unsigned short f2bf(float f){
  unsigned int u = __float_as_uint(f);
  u += 0x7fffu + ((u >> 16) & 1u);   // round-to-nearest-even
  return (unsigned short)(u >> 16);
}

// ---------------------------------------------------------------------------
// K1: gate GEMV + chunk-local scan.  DIAGNOSTIC build: main path repeats its
// (idempotent) work REP_ times so the dispatch exceeds the ~79us fill cutoff
// and appears in rocprof top-5 with full counters. dur/REP_ = true t_g.
// ---------------------------------------------------------------------------
__global__ __launch_bounds__(512) void k_gates(
    const float* __restrict__ x,
    const float* __restrict__ inc_w, const float* __restrict__ inc_b,
    const float* __restrict__ reset_w, const float* __restrict__ reset_b,
    float* __restrict__ out_incl,
    float* __restrict__ cl, float* __restrict__ kc,
    float* __restrict__ sumP, float* __restrict__ sumQ,
    const float* __restrict__ read_w, unsigned short* __restrict__ Bt)
{
  const int blk  = blockIdx.x;
  if (blk >= 512){
    const int idx0 = ((blk - 512)*512 + threadIdx.x)*4;   // multiple of 4
    const int n  = idx0 >> 6;
    const int kk = idx0 & 63;
    ushort4 v;
    v.x = f2bf(read_w[(size_t)(kk+0)*D_ + n]);
    v.y = f2bf(read_w[(size_t)(kk+1)*D_ + n]);
    v.z = f2bf(read_w[(size_t)(kk+2)*D_ + n]);
    v.w = f2bf(read_w[(size_t)(kk+3)*D_ + n]);
    *(ushort4*)(Bt + idx0) = v;
    return;
  }

  __shared__ float s_keep[128];
  __shared__ float s_inc[128];
  const int b    = blk >> 7;          // /NCH_
  const int ch   = blk & 127;
  const int tid  = threadIdx.x;
  const int w    = tid >> 6;
  const int lane = tid & 63;

  // loop-invariant weights
  float4 wia[4], wib[4], wra[4], wrb[4];
  #pragma unroll
  for (int i = 0; i < 4; ++i){
    const int d0 = i*256 + lane*4;
    const float4* pi = (const float4*)(inc_w + d0*2);
    wia[i] = pi[0]; wib[i] = pi[1];
    const float4* pr = (const float4*)(reset_w + d0*2);
    wra[i] = pr[0]; wrb[i] = pr[1];
  }
  const float bi0 = inc_b[0], bi1 = inc_b[1];
  const float br0 = reset_b[0], br1 = reset_b[1];
  const int row0 = b*L_ + ch*64 + w*8;

  #pragma unroll 1
  for (int rep = 0; rep < REP_; ++rep){
    floatx4 xc[4], xn[4];
    {
      const floatx4* xr = (const floatx4*)(x + (size_t)row0 * D_);
      #pragma unroll
      for (int i = 0; i < 4; ++i) xc[i] = __builtin_nontemporal_load(xr + i*64 + lane);
    }
    #pragma unroll
    for (int r = 0; r < 8; ++r){
      if (r < 7){
        const floatx4* xr = (const floatx4*)(x + (size_t)(row0 + r + 1) * D_);
        #pragma unroll
        for (int i = 0; i < 4; ++i) xn[i] = __builtin_nontemporal_load(xr + i*64 + lane);
      }
      float ai0=0.f, ai1=0.f, ar0=0.f, ar1=0.f;
      #pragma unroll
      for (int i = 0; i < 4; ++i){
        const floatx4 v = xc[i];
        ai0 += v[0]*wia[i].x + v[1]*wia[i].z + v[2]*wib[i].x + v[3]*wib[i].z;
        ai1 += v[0]*wia[i].y + v[1]*wia[i].w + v[2]*wib[i].y + v[3]*wib[i].w;
        ar0 += v[0]*wra[i].x + v[1]*wra[i].z + v[2]*wrb[i].x + v[3]*wrb[i].z;
        ar1 += v[0]*wra[i].y + v[1]*wra[i].w + v[2]*wrb[i].y + v[3]*wrb[i].w;
      }
      #pragma unroll
      for (int m = 1; m < 64; m <<= 1){
        ai0 += __shfl_xor(ai0, m);
        ai1 += __shfl_xor(ai1, m);
        ar0 += __shfl_xor(ar0, m);
        ar1 += __shfl_xor(ar1, m);
      }
      if (lane == 0){
        const int row = row0 + r;
        const float il0 = ai0 + bi0, il1 = ai1 + bi1;
        const float rl0 = ar0 + br0, rl1 = ar1 + br1;
        out_incl[(size_t)row*2 + 0] = il0;
        out_incl[(size_t)row*2 + 1] = il1;
        const int lr = w*8 + r;
        s_inc [lr*2+0] = 1.f / (1.f + __expf(-il0));
        s_inc [lr*2+1] = 1.f / (1.f + __expf(-il1));
        s_keep[lr*2+0] = 1.f - 1.f / (1.f + __expf(-rl0));
        s_keep[lr*2+1] = 1.f - 1.f / (1.f + __expf(-rl1));
      }
      #pragma unroll
      for (int i = 0; i < 4; ++i) xc[i] = xn[i];
    }
    __syncthreads();

    if (tid < 128){
      const int k = w;
      float P = s_keep[lane*2 + k];
      float Q = s_inc [lane*2 + k];
      #pragma unroll
      for (int ofs = 1; ofs < 64; ofs <<= 1){
        const float Pp = __shfl_up(P, ofs);
        const float Qp = __shfl_up(Q, ofs);
        if (lane >= ofs){ Q = Q + P * Qp; P = P * Pp; }
      }
      const int row = b*L_ + ch*64 + lane;
      cl[(size_t)row*2 + k] = Q;
      kc[(size_t)row*2 + k] = P;
      if (lane == 63){
        const int seq = b*2 + k;
        sumP[seq*NCH_ + ch] = P;
        sumQ[seq*NCH_ + ch] = Q;
      }
    }
    __syncthreads();   // protect s_keep/s_inc reuse across reps
  }
}

// ---------------------------------------------------------------------------
// K2 (R2 structure, measured best).  DIAGNOSTIC build: scan+trig+MFMA+store
// repeated REP_ times (idempotent). dur/REP_ = true t_f.
// ---------------------------------------------------------------------------
__global__ __launch_bounds__(256) void k_fused(
    const float* __restrict__ cl, const float* __restrict__ kc,
    const float* __restrict__ sumP, const float* __restrict__ sumQ,
    const unsigned short* __restrict__ Bt,
    const float* __restrict__ read_b,
    float* __restrict__ out_cnt, float* __restrict__ out)
{
  __shared__ float s_carry[2];
  const int tid  = threadIdx.x;
  const int w    = tid >> 6;
  const int lane = tid & 63;
  const int stripe = blockIdx.x >> 1;
  const int half   = blockIdx.x & 1;
  const int rowBase0 = stripe * 64;
  const int b  = rowBase0 >> 13;
  const int ch = stripe & 127;
  const int m    = lane & 15;
  const int quad = lane >> 4;
  const int colBase = half*512 + w*128;

  // loop-invariant: B fragments + bias
  short8 b0[8], b1[8];
  float  bias[8];
  #pragma unroll
  for (int ct = 0; ct < 8; ++ct){
    const int n = colBase + ct*16 + m;
    const short8* bp = (const short8*)(Bt + (size_t)n * 64);
    b0[ct]  = bp[quad];
    b1[ct]  = bp[4 + quad];
    bias[ct] = read_b[n];
  }

  const float TWO_PI_INV = 0.15915494309189535f;
  const float STEP = 0.5743491774985175f;        // 2^-0.8
  const float INVF0 = (quad & 1) ? 0.011841535573494211f /* 2^-6.4 */ : 1.0f;
  const bool use_cos = (quad >> 1) != 0;

  #pragma unroll 1
  for (int rep = 0; rep < REP_; ++rep){
    // ---- exclusive carry scan ----
    if (w < 2){
      const int seq = b*2 + w;
      const float* P0 = sumP + seq*NCH_;
      const float* Q0 = sumQ + seq*NCH_;
      float P = P0[lane], Q = Q0[lane];
      #pragma unroll
      for (int ofs = 1; ofs < 64; ofs <<= 1){
        const float Pp = __shfl_up(P, ofs);
        const float Qp = __shfl_up(Q, ofs);
        if (lane >= ofs){ Q = Q + P * Qp; P = P * Pp; }
      }
      float carry = 0.f;
      if (ch > 0 && ch <= 64) carry = __shfl(Q, ch-1);
      const float Qc = __shfl(Q, 63);
      float P2 = P0[64 + lane], Q2 = Q0[64 + lane];
      #pragma unroll
      for (int ofs = 1; ofs < 64; ofs <<= 1){
        const float Pp = __shfl_up(P2, ofs);
        const float Qp = __shfl_up(Q2, ofs);
        if (lane >= ofs){ Q2 = Q2 + P2 * Qp; P2 = P2 * Pp; }
      }
      Q2 = Q2 + P2 * Qc;
      if (ch >= 65) carry = __shfl(Q2, ch-65);
      if (lane == 0) s_carry[w] = carry;
    }
    __syncthreads();
    const float carry0 = s_carry[0];
    const float carry1 = s_carry[1];

    #pragma unroll
    for (int rt = 0; rt < 4; ++rt){
      const int rowBase = rowBase0 + rt*16;
      const int row = rowBase + m;

      const float2 clv = *(const float2*)(cl + (size_t)row*2);
      const float2 kcv = *(const float2*)(kc + (size_t)row*2);
      const float c0 = clv.x + kcv.x * carry0;
      const float c1 = clv.y + kcv.y * carry1;
      if (half == 0 && w == 0 && lane < 16){
        ((float2*)out_cnt)[row] = make_float2(c0, c1);
      }

      float invf = INVF0;
      short8 a0, a1;
      #pragma unroll
      for (int j = 0; j < 8; ++j){
        float r0 = c0 * invf * TWO_PI_INV; r0 -= floorf(r0);
        float r1 = c1 * invf * TWO_PI_INV; r1 -= floorf(r1);
        const float e0 = use_cos ? __builtin_amdgcn_cosf(r0) : __builtin_amdgcn_sinf(r0);
        const float e1 = use_cos ? __builtin_amdgcn_cosf(r1) : __builtin_amdgcn_sinf(r1);
        a0[j] = (short)f2bf(e0);
        a1[j] = (short)f2bf(e1);
        invf *= STEP;
      }

      floatx4 acc[8];
      #pragma unroll
      for (int ct = 0; ct < 8; ++ct) acc[ct] = (floatx4){0.f,0.f,0.f,0.f};
      #pragma unroll
      for (int ct = 0; ct < 8; ++ct){
        acc[ct] = __builtin_amdgcn_mfma_f32_16x16x32_bf16(a0, b0[ct], acc[ct], 0, 0, 0);
        acc[ct] = __builtin_amdgcn_mfma_f32_16x16x32_bf16(a1, b1[ct], acc[ct], 0, 0, 0);
      }

      #pragma unroll
      for (int ct = 0; ct < 8; ++ct){
        const int col = colBase + ct*16 + m;
        #pragma unroll
        for (int r = 0; r < 4; ++r){
          const int orow = rowBase + quad*4 + r;
          __builtin_nontemporal_store(acc[ct][r] + bias[ct], &out[(size_t)orow*D_ + col]);
        }
      }
    }
    __syncthreads();   // protect s_carry reuse across reps
  }
}

// ---------------------------------------------------------------------------
extern "C" void kernel_launch(void* const* d_in, const int* in_sizes, int n_in,
                              void* d_out, int out_size, void* d_ws, size_t ws_size,
                              hipStream_t stream) {
  const float* x       = (const float*)d_in[0];
  const float* inc_w   = (const float*)d_in[1];
  const float* inc_b   = (const float*)d_in[2];
  const float* reset_w = (const float*)d_in[3];
  const float* reset_b = (const float*)d_in[4];
  const float* read_w  = (const float*)d_in[5];
  const float* read_b  = (const float*)d_in[6];

  float* out      = (float*)d_out;
  float* out_incl = out + (size_t)ROWS_ * D_;        // 33554432
  float* out_cnt  = out_incl + ROWS_ * 2;            // +65536

  char* ws = (char*)d_ws;
  float* cl    = (float*)(ws + 0);                   // 262144 B
  float* kc    = (float*)(ws + 262144);              // 262144 B
  float* sumP  = (float*)(ws + 524288);              // 4096 B
  float* sumQ  = (float*)(ws + 528384);              // 4096 B
  unsigned short* Bt  = (unsigned short*)(ws + 532480);  // 128 KB

  k_gates<<<dim3(544),  dim3(512), 0, stream>>>(x, inc_w, inc_b, reset_w, reset_b,
                                                out_incl, cl, kc, sumP, sumQ,
                                                read_w, Bt);
  k_fused<<<dim3(1024), dim3(256), 0, stream>>>(cl, kc, sumP, sumQ, Bt, read_b,
                                                out_cnt, out);
}

// Round 7
// 245.048 us; speedup vs baseline: 2.1865x; 2.1865x over previous
//
#include <hip/hip_runtime.h>

#define B_    4
#define L_    8192
#define D_    1024
#define ROWS_ 32768
#define NCH_  128   // chunks of 64 rows per sequence

typedef __attribute__((ext_vector_type(8))) short  short8;
typedef __attribute__((ext_vector_type(4))) float  floatx4;

__device__ __forceinline__ unsigned short f2bf(float f){
  unsigned int u = __float_as_uint(f);
  u += 0x7fffu + ((u >> 16) & 1u);   // round-to-nearest-even
  return (unsigned short)(u >> 16);
}

// ---------------------------------------------------------------------------
// K1: gate GEMV (4 dots of length 1024 per row) + chunk-local scan (64 rows)
// blocks 0..511: (b,chunk), 512 threads (8 waves x 8 rows each)
// blocks 512..543: transpose+convert read_w (64x1024 f32) -> Bt (1024x64 bf16)
// MEASURED (R6): t_g ~= 20us ~= the 134MB read floor at 6.5TB/s. BW-bound,
// do not touch.
// ---------------------------------------------------------------------------
__global__ __launch_bounds__(512) void k_gates(
    const float* __restrict__ x,
    const float* __restrict__ inc_w, const float* __restrict__ inc_b,
    const float* __restrict__ reset_w, const float* __restrict__ reset_b,
    float* __restrict__ out_incl,
    float* __restrict__ cl, float* __restrict__ kc,
    float* __restrict__ sumP, float* __restrict__ sumQ,
    const float* __restrict__ read_w, unsigned short* __restrict__ Bt)
{
  const int blk  = blockIdx.x;
  if (blk >= 512){
    // Bt build: 32 blocks x 512 threads x 4 elements = 65536
    const int idx0 = ((blk - 512)*512 + threadIdx.x)*4;   // multiple of 4
    const int n  = idx0 >> 6;            // same for all 4 (4 | 64)
    const int kk = idx0 & 63;
    ushort4 v;
    v.x = f2bf(read_w[(size_t)(kk+0)*D_ + n]);
    v.y = f2bf(read_w[(size_t)(kk+1)*D_ + n]);
    v.z = f2bf(read_w[(size_t)(kk+2)*D_ + n]);
    v.w = f2bf(read_w[(size_t)(kk+3)*D_ + n]);
    *(ushort4*)(Bt + idx0) = v;
    return;
  }

  __shared__ float s_keep[128];
  __shared__ float s_inc[128];
  const int b    = blk >> 7;          // /NCH_
  const int ch   = blk & 127;
  const int tid  = threadIdx.x;
  const int w    = tid >> 6;
  const int lane = tid & 63;

  // per-lane weights for d in {i*256 + 4*lane .. +3}, both k, both gates
  float4 wia[4], wib[4], wra[4], wrb[4];
  #pragma unroll
  for (int i = 0; i < 4; ++i){
    const int d0 = i*256 + lane*4;
    const float4* pi = (const float4*)(inc_w + d0*2);
    wia[i] = pi[0]; wib[i] = pi[1];
    const float4* pr = (const float4*)(reset_w + d0*2);
    wra[i] = pr[0]; wrb[i] = pr[1];
  }
  const float bi0 = inc_b[0], bi1 = inc_b[1];
  const float br0 = reset_b[0], br1 = reset_b[1];

  const int row0 = b*L_ + ch*64 + w*8;
  floatx4 xc[4], xn[4];
  {
    const floatx4* xr = (const floatx4*)(x + (size_t)row0 * D_);
    #pragma unroll
    for (int i = 0; i < 4; ++i) xc[i] = __builtin_nontemporal_load(xr + i*64 + lane);
  }
  #pragma unroll
  for (int r = 0; r < 8; ++r){
    if (r < 7){  // prefetch next row while computing this one
      const floatx4* xr = (const floatx4*)(x + (size_t)(row0 + r + 1) * D_);
      #pragma unroll
      for (int i = 0; i < 4; ++i) xn[i] = __builtin_nontemporal_load(xr + i*64 + lane);
    }
    float ai0=0.f, ai1=0.f, ar0=0.f, ar1=0.f;
    #pragma unroll
    for (int i = 0; i < 4; ++i){
      const floatx4 v = xc[i];
      ai0 += v[0]*wia[i].x + v[1]*wia[i].z + v[2]*wib[i].x + v[3]*wib[i].z;
      ai1 += v[0]*wia[i].y + v[1]*wia[i].w + v[2]*wib[i].y + v[3]*wib[i].w;
      ar0 += v[0]*wra[i].x + v[1]*wra[i].z + v[2]*wrb[i].x + v[3]*wrb[i].z;
      ar1 += v[0]*wra[i].y + v[1]*wra[i].w + v[2]*wrb[i].y + v[3]*wrb[i].w;
    }
    #pragma unroll
    for (int m = 1; m < 64; m <<= 1){
      ai0 += __shfl_xor(ai0, m);
      ai1 += __shfl_xor(ai1, m);
      ar0 += __shfl_xor(ar0, m);
      ar1 += __shfl_xor(ar1, m);
    }
    if (lane == 0){
      const int row = row0 + r;
      const float il0 = ai0 + bi0, il1 = ai1 + bi1;
      const float rl0 = ar0 + br0, rl1 = ar1 + br1;
      out_incl[(size_t)row*2 + 0] = il0;
      out_incl[(size_t)row*2 + 1] = il1;
      const int lr = w*8 + r;
      s_inc [lr*2+0] = 1.f / (1.f + __expf(-il0));
      s_inc [lr*2+1] = 1.f / (1.f + __expf(-il1));
      s_keep[lr*2+0] = 1.f - 1.f / (1.f + __expf(-rl0));
      s_keep[lr*2+1] = 1.f - 1.f / (1.f + __expf(-rl1));
    }
    #pragma unroll
    for (int i = 0; i < 4; ++i) xc[i] = xn[i];
  }
  __syncthreads();

  // chunk-local inclusive scan: wave 0 -> k=0, wave 1 -> k=1, lane j = local row j
  if (tid < 128){
    const int k = w;
    float P = s_keep[lane*2 + k];   // keep
    float Q = s_inc [lane*2 + k];   // inc
    #pragma unroll
    for (int ofs = 1; ofs < 64; ofs <<= 1){
      const float Pp = __shfl_up(P, ofs);
      const float Qp = __shfl_up(Q, ofs);
      if (lane >= ofs){ Q = Q + P * Qp; P = P * Pp; }
    }
    const int row = b*L_ + ch*64 + lane;
    cl[(size_t)row*2 + k] = Q;      // zero-state local counter
    kc[(size_t)row*2 + k] = P;      // cumulative keep product
    if (lane == 63){
      const int seq = b*2 + k;
      sumP[seq*NCH_ + ch] = P;
      sumQ[seq*NCH_ + ch] = Q;
    }
  }
}

// ---------------------------------------------------------------------------
// K2 (fused carry-scan + emb + GEMM), R2 register-blocked structure.
// R6 rocprof finding: nontemporal out-stores caused partial-line (64B) HBM
// writebacks -> TCC read-modify-write: FETCH 147MB/pass (= out size!) on a
// kernel that reads <1MB; 320MB moved vs 135 ideal; t_f = 43us vs ~22 floor.
// FIX: PLAIN stores (write-allocate; each wave's 512B-aligned 128-col range
// becomes fully dirty in L2 within its ct-loop -> full-line writebacks,
// FETCH ~0) + R4-verified operand-swapped MFMA so each lane stores float4.
// ---------------------------------------------------------------------------
__global__ __launch_bounds__(256) void k_fused(
    const float* __restrict__ cl, const float* __restrict__ kc,
    const float* __restrict__ sumP, const float* __restrict__ sumQ,
    const unsigned short* __restrict__ Bt,
    const float* __restrict__ read_b,
    float* __restrict__ out_cnt, float* __restrict__ out)
{
  __shared__ float s_carry[2];
  const int tid  = threadIdx.x;
  const int w    = tid >> 6;
  const int lane = tid & 63;
  const int stripe = blockIdx.x >> 1;       // 512 row-stripes of 64 rows
  const int half   = blockIdx.x & 1;        // which 512-col half
  const int rowBase0 = stripe * 64;
  const int b  = rowBase0 >> 13;            // /L_
  const int ch = stripe & 127;              // chunk index within sequence
  const int m    = lane & 15;
  const int quad = lane >> 4;
  const int colBase = half*512 + w*128;     // 8 col-tiles of 16 per wave

  // ---- exclusive carry for chunk ch of sequences (b,k=0) and (b,k=1) ----
  if (w < 2){
    const int seq = b*2 + w;
    const float* P0 = sumP + seq*NCH_;
    const float* Q0 = sumQ + seq*NCH_;
    float P = P0[lane], Q = Q0[lane];
    #pragma unroll
    for (int ofs = 1; ofs < 64; ofs <<= 1){
      const float Pp = __shfl_up(P, ofs);
      const float Qp = __shfl_up(Q, ofs);
      if (lane >= ofs){ Q = Q + P * Qp; P = P * Pp; }
    }
    float carry = 0.f;
    if (ch > 0 && ch <= 64) carry = __shfl(Q, ch-1);
    const float Qc = __shfl(Q, 63);
    float P2 = P0[64 + lane], Q2 = Q0[64 + lane];
    #pragma unroll
    for (int ofs = 1; ofs < 64; ofs <<= 1){
      const float Pp = __shfl_up(P2, ofs);
      const float Qp = __shfl_up(Q2, ofs);
      if (lane >= ofs){ Q2 = Q2 + P2 * Qp; P2 = P2 * Pp; }
    }
    Q2 = Q2 + P2 * Qc;                      // fold in first-half total
    if (ch >= 65) carry = __shfl(Q2, ch-65);
    if (lane == 0) s_carry[w] = carry;
  }
  __syncthreads();
  const float carry0 = s_carry[0];
  const float carry1 = s_carry[1];

  // ---- B fragments + bias (float4 per ct), resident across the 4 row-tiles ----
  short8 b0[8], b1[8];
  floatx4 bias4[8];
  #pragma unroll
  for (int ct = 0; ct < 8; ++ct){
    const int n = colBase + ct*16 + m;
    const short8* bp = (const short8*)(Bt + (size_t)n * 64);
    b0[ct] = bp[quad];
    b1[ct] = bp[4 + quad];
    bias4[ct] = *(const floatx4*)(read_b + colBase + ct*16 + quad*4);
  }

  const float TWO_PI_INV = 0.15915494309189535f;
  const float STEP = 0.5743491774985175f;        // 2^-0.8
  const float INVF0 = (quad & 1) ? 0.011841535573494211f /* 2^-6.4 */ : 1.0f;
  const bool use_cos = (quad >> 1) != 0;

  #pragma unroll
  for (int rt = 0; rt < 4; ++rt){
    const int rowBase = rowBase0 + rt*16;
    const int row = rowBase + m;

    // ---- counters for this lane's row ----
    const float2 clv = *(const float2*)(cl + (size_t)row*2);
    const float2 kcv = *(const float2*)(kc + (size_t)row*2);
    const float c0 = clv.x + kcv.x * carry0;
    const float c1 = clv.y + kcv.y * carry1;
    if (half == 0 && w == 0 && lane < 16){
      ((float2*)out_cnt)[row] = make_float2(c0, c1);
    }

    // ---- A fragments in-register ----
    float invf = INVF0;
    short8 a0, a1;
    #pragma unroll
    for (int j = 0; j < 8; ++j){
      float r0 = c0 * invf * TWO_PI_INV; r0 -= floorf(r0);
      float r1 = c1 * invf * TWO_PI_INV; r1 -= floorf(r1);
      const float e0 = use_cos ? __builtin_amdgcn_cosf(r0) : __builtin_amdgcn_sinf(r0);
      const float e1 = use_cos ? __builtin_amdgcn_cosf(r1) : __builtin_amdgcn_sinf(r1);
      a0[j] = (short)f2bf(e0);
      a1[j] = (short)f2bf(e1);
      invf *= STEP;
    }

    // ---- operand-swapped MFMA: lane holds out[rowBase+m][ct*16+quad*4+reg] ----
    floatx4 acc[8];
    #pragma unroll
    for (int ct = 0; ct < 8; ++ct) acc[ct] = (floatx4){0.f,0.f,0.f,0.f};
    #pragma unroll
    for (int ct = 0; ct < 8; ++ct){
      acc[ct] = __builtin_amdgcn_mfma_f32_16x16x32_bf16(b0[ct], a0, acc[ct], 0, 0, 0);
      acc[ct] = __builtin_amdgcn_mfma_f32_16x16x32_bf16(b1[ct], a1, acc[ct], 0, 0, 0);
    }

    // ---- epilogue: bias + PLAIN float4 stores (L2 merges to full lines) ----
    const int orow = rowBase + m;
    float* orp = out + (size_t)orow*D_;
    #pragma unroll
    for (int ct = 0; ct < 8; ++ct){
      const int col0 = colBase + ct*16 + quad*4;
      *(floatx4*)(orp + col0) = acc[ct] + bias4[ct];
    }
  }
}

// ---------------------------------------------------------------------------
extern "C" void kernel_launch(void* const* d_in, const int* in_sizes, int n_in,
                              void* d_out, int out_size, void* d_ws, size_t ws_size,
                              hipStream_t stream) {
  const float* x       = (const float*)d_in[0];
  const float* inc_w   = (const float*)d_in[1];
  const float* inc_b   = (const float*)d_in[2];
  const float* reset_w = (const float*)d_in[3];
  const float* reset_b = (const float*)d_in[4];
  const float* read_w  = (const float*)d_in[5];
  const float* read_b  = (const float*)d_in[6];

  float* out      = (float*)d_out;
  float* out_incl = out + (size_t)ROWS_ * D_;        // 33554432
  float* out_cnt  = out_incl + ROWS_ * 2;            // +65536

  char* ws = (char*)d_ws;
  float* cl    = (float*)(ws + 0);                   // 262144 B
  float* kc    = (float*)(ws + 262144);              // 262144 B
  float* sumP  = (float*)(ws + 524288);              // 4096 B
  float* sumQ  = (float*)(ws + 528384);              // 4096 B
  unsigned short* Bt  = (unsigned short*)(ws + 532480);  // 128 KB

  k_gates<<<dim3(544),  dim3(512), 0, stream>>>(x, inc_w, inc_b, reset_w, reset_b,
                                                out_incl, cl, kc, sumP, sumQ,
                                                read_w, Bt);
  k_fused<<<dim3(1024), dim3(256), 0, stream>>>(cl, kc, sumP, sumQ, Bt, read_b,
                                                out_cnt, out);
}